// Round 1
// baseline (62.997 us; speedup 1.0000x reference)
//
#include <hip/hip_runtime.h>
#include <math.h>

// ProbAttention at B=1, L=S=128, H=8, D=1, u=25.
// Key simplifications (verified against the reference semantics):
//  * reshape(B,H,L,-1) on a (B,L,H,D) array with B=1,D=1 is a flat
//    reinterpretation -> q_flat[h*L + l].
//  * masked scores are where(mask, -inf, ZEROS) -> softmax is uniform over
//    the causal prefix l <= idx; upd = prefix-mean of v.
//  * cumsum over the size-1 D axis is identity -> ctx = v.
//  * scatter order of idx is irrelevant; only the top-k SET matters.
//    jax.lax.top_k tie-break = lowest index first -> rank with (>, or == && s<l).
//
// This revision: barrier-minimal variant (2 __syncthreads instead of 16).
//  * prefix sum of v via intra-wave __shfl_up scan (6 steps, register-only)
//    + one LDS word to carry wave0's total into wave1.
//  * ablation purpose: if dur_us does not move, the measured time is the
//    harness poison-fill floor (39.4us @ 85% HBM peak) + fixed dispatch
//    overhead, and the kernel is already negligible.

#define LSEQ 128
#define NHEAD 8

__global__ __launch_bounds__(LSEQ) void probattn_kernel(
    const float* __restrict__ q, const float* __restrict__ k,
    const float* __restrict__ v, const int* __restrict__ kseq,
    float* __restrict__ out, int U) {
  const int h = blockIdx.x;
  const int l = threadIdx.x;   // 0..127
  const int lane = l & 63;
  const int wave = l >> 6;

  __shared__ float Ks[64];     // gathered keys (U <= 64)
  __shared__ float M[LSEQ];    // sparsity measure per query position
  __shared__ float wsum;       // wave0 scan total

  if (l < U) Ks[l] = k[h * LSEQ + kseq[l]];
  const float ql = q[h * LSEQ + l];
  const float vl = v[h * LSEQ + l];
  __syncthreads();  // Ks visible

  // M[l] = max_j(q*Ks_j) - sum_j(q*Ks_j)/S   (S = 128, /128 is exact)
  float mx = -INFINITY, sm = 0.0f;
  for (int j = 0; j < U; ++j) {
    const float p = ql * Ks[j];
    mx = fmaxf(mx, p);
    sm += p;
  }
  const float Ml = mx - sm * (1.0f / (float)LSEQ);
  M[l] = Ml;

  // Inclusive prefix sum of v: register shuffle scan within each 64-lane
  // wave, then carry wave0's total into wave1 through one LDS word.
  float incl = vl;
#pragma unroll
  for (int off = 1; off < 64; off <<= 1) {
    const float n = __shfl_up(incl, off);
    if (lane >= off) incl += n;
  }
  if (l == 63) wsum = incl;    // wave0 total
  __syncthreads();             // M[] and wsum visible
  if (wave == 1) incl += wsum;

  // rank of M[l] with top_k's lowest-index tie-break
  int rank = 0;
  for (int s = 0; s < LSEQ; ++s) {
    const float Ms = M[s];
    rank += (Ms > Ml) || (Ms == Ml && s < l);
  }

  out[h * LSEQ + l] = (rank < U) ? (incl / (float)(l + 1)) : vl;
}

extern "C" void kernel_launch(void* const* d_in, const int* in_sizes, int n_in,
                              void* d_out, int out_size, void* d_ws, size_t ws_size,
                              hipStream_t stream) {
  const float* q = (const float*)d_in[0];
  const float* k = (const float*)d_in[1];
  const float* v = (const float*)d_in[2];
  const int* kseq = (const int*)d_in[3];
  float* out = (float*)d_out;
  const int U = in_sizes[3];  // 25

  probattn_kernel<<<NHEAD, LSEQ, 0, stream>>>(q, k, v, kseq, out, U);
}